// Round 7
// baseline (334.744 us; speedup 1.0000x reference)
//
#include <hip/hip_runtime.h>
#include <hip/hip_bf16.h>
#include <float.h>

// Problem constants
#define BB    2
#define NSEQ  2048
#define CDIM  1024
#define HH    16
#define DD    64
#define KKEEP 1228

typedef __attribute__((ext_vector_type(8))) short short8_t;
typedef __attribute__((ext_vector_type(4))) short short4_t;
typedef __attribute__((ext_vector_type(4))) float f32x4;
typedef __attribute__((ext_vector_type(4))) float float4_t;
typedef __bf16 bf16x8 __attribute__((ext_vector_type(8)));

static __device__ __forceinline__ short f2bf(float x) {
  __hip_bfloat16 h = __float2bfloat16(x);
  short s;
  __builtin_memcpy(&s, &h, 2);
  return s;
}

static __device__ __forceinline__ float bf2f(short s) {
  unsigned u = ((unsigned)(unsigned short)s) << 16;
  float f;
  __builtin_memcpy(&f, &u, 4);
  return f;
}

static __device__ __forceinline__ f32x4 mfma16(bf16x8 a, bf16x8 b, f32x4 c) {
  return __builtin_amdgcn_mfma_f32_16x16x32_bf16(a, b, c, 0, 0, 0);
}

// ---------------- cast kernels ----------------
__global__ __launch_bounds__(256) void cast_f32_bf16_kernel(
    const float* __restrict__ src, short* __restrict__ dst, int n4) {
  int i = blockIdx.x * 256 + threadIdx.x;
  if (i >= n4) return;
  float4_t v = ((const float4_t*)src)[i];
  short4_t o;
  o[0] = f2bf(v[0]); o[1] = f2bf(v[1]); o[2] = f2bf(v[2]); o[3] = f2bf(v[3]);
  ((short4_t*)dst)[i] = o;
}

// Permute W_qkv rows: dst row rr = c*1024 + h*64 + d  <-  src row h*192 + d*3 + c
__global__ __launch_bounds__(256) void cast_wqkv_kernel(
    const float* __restrict__ w, short* __restrict__ dst) {
  int rr = blockIdx.x;              // 0..3071
  int c = rr >> 10, hd = rr & 1023;
  int h = hd >> 6, d = hd & 63;
  int srow = h * 192 + d * 3 + c;
  int col = threadIdx.x * 4;
  float4_t v = *(const float4_t*)(w + (size_t)srow * CDIM + col);
  short4_t o;
  o[0] = f2bf(v[0]); o[1] = f2bf(v[1]); o[2] = f2bf(v[2]); o[3] = f2bf(v[3]);
  *(short4_t*)(dst + (size_t)rr * CDIM + col) = o;
}

// ---------------- GEMM: C[M,N] = A[M,K] * B[N,K]^T (both bf16, fp32 acc) ----------------
template <int EPI>
__global__ __launch_bounds__(256) void gemm_bt_kernel(
    const short* __restrict__ A, const short* __restrict__ B, int K, int N,
    float* __restrict__ outF, short* __restrict__ outQ,
    short* __restrict__ outK, short* __restrict__ outV) {
  __shared__ short lA[128 * 32];
  __shared__ short lB[128 * 32];
  int m0 = blockIdx.y * 128, n0 = blockIdx.x * 128;
  int tid = threadIdx.x, lane = tid & 63;
  int w = tid >> 6;
  int lq = lane & 15, lg = lane >> 4;
  int wm = w >> 1, wn = w & 1;

  f32x4 acc[4][4];
#pragma unroll
  for (int m = 0; m < 4; ++m)
#pragma unroll
    for (int n = 0; n < 4; ++n) acc[m][n] = (f32x4){0.f, 0.f, 0.f, 0.f};

  const int c0 = tid, c1 = tid + 256;
  for (int k0 = 0; k0 < K; k0 += 32) {
    short8_t a0 = *(const short8_t*)(A + (size_t)(m0 + (c0 >> 2)) * K + k0 + (c0 & 3) * 8);
    short8_t a1 = *(const short8_t*)(A + (size_t)(m0 + (c1 >> 2)) * K + k0 + (c1 & 3) * 8);
    short8_t b0 = *(const short8_t*)(B + (size_t)(n0 + (c0 >> 2)) * K + k0 + (c0 & 3) * 8);
    short8_t b1 = *(const short8_t*)(B + (size_t)(n0 + (c1 >> 2)) * K + k0 + (c1 & 3) * 8);
    *(short8_t*)(lA + c0 * 8) = a0;
    *(short8_t*)(lA + c1 * 8) = a1;
    *(short8_t*)(lB + c0 * 8) = b0;
    *(short8_t*)(lB + c1 * 8) = b1;
    __syncthreads();
    bf16x8 af[4], bf[4];
#pragma unroll
    for (int m = 0; m < 4; ++m)
      af[m] = *(const bf16x8*)(lA + (wm * 64 + m * 16 + lq) * 32 + lg * 8);
#pragma unroll
    for (int n = 0; n < 4; ++n)
      bf[n] = *(const bf16x8*)(lB + (wn * 64 + n * 16 + lq) * 32 + lg * 8);
#pragma unroll
    for (int m = 0; m < 4; ++m)
#pragma unroll
      for (int n = 0; n < 4; ++n) acc[m][n] = mfma16(af[m], bf[n], acc[m][n]);
    __syncthreads();
  }

#pragma unroll
  for (int m = 0; m < 4; ++m)
#pragma unroll
    for (int n = 0; n < 4; ++n) {
      int row_b = m0 + wm * 64 + m * 16 + lg * 4;
      int col = n0 + wn * 64 + n * 16 + lq;
#pragma unroll
      for (int r = 0; r < 4; ++r) {
        float v = acc[m][n][r];
        int row = row_b + r;
        if constexpr (EPI == 1) {
          outF[(size_t)row * N + col] = v;
        } else {
          int c = col >> 10, cc = col & 1023;
          int bb2 = row >> 11, nn = row & 2047;
          int hh2 = cc >> 6, dd2 = cc & 63;
          short val = f2bf(v);
          if (c == 0)
            outQ[((size_t)(bb2 * HH + hh2) * NSEQ + nn) * DD + dd2] = val;
          else if (c == 1)
            outK[((size_t)(bb2 * HH + hh2) * NSEQ + nn) * DD + dd2] = val;
          else
            outV[((size_t)(bb2 * HH + hh2) * DD + dd2) * NSEQ + nn] = val;
        }
      }
    }
}

// ---------------- top-k selection -> keep bitmap + jmin (stable: value desc, index asc) ----
__global__ __launch_bounds__(256) void topk_kernel(const int* __restrict__ seq_mask,
                                                   unsigned* __restrict__ keepw,
                                                   int* __restrict__ jminb) {
  __shared__ int hist[10];
  __shared__ int vals[NSEQ];
  __shared__ int seqc[256];
  __shared__ unsigned wbuf[64];
  __shared__ int sT, sNeed, sMin;
  int bh = blockIdx.x, tid = threadIdx.x;
  if (tid < 10) hist[tid] = 0;
  if (tid < 64) wbuf[tid] = 0;
  if (tid == 0) sMin = NSEQ;
  __syncthreads();
  const int* sm = seq_mask + (size_t)bh * NSEQ;
  for (int i = tid; i < NSEQ; i += 256) {
    int v = sm[i];
    vals[i] = v;
    atomicAdd(&hist[v], 1);
  }
  __syncthreads();
  if (tid == 0) {
    int cum = 0, t = 0;
    for (int v = 9; v >= 0; --v) {
      int hv = hist[v];
      if (cum + hv >= KKEEP) { t = v; break; }
      cum += hv;
    }
    sT = t;
    sNeed = KKEEP - cum;   // ties (value==t) kept, lowest indices first
  }
  __syncthreads();
  int t = sT, need = sNeed;
  int base = tid * 8, leq = 0;
  int lv[8];
#pragma unroll
  for (int j = 0; j < 8; ++j) {
    lv[j] = vals[base + j];
    leq += (lv[j] == t);
  }
  seqc[tid] = leq;
  __syncthreads();
  for (int off = 1; off < 256; off <<= 1) {
    int a = 0;
    if (tid >= off) a = seqc[tid - off];
    __syncthreads();
    seqc[tid] += a;
    __syncthreads();
  }
  int eqp = seqc[tid] - leq;  // exclusive prefix of (v==t)
  unsigned mybits = 0;
#pragma unroll
  for (int j = 0; j < 8; ++j) {
    int v = lv[j];
    bool kept = (v > t) || (v == t && eqp < need);
    if (v == t) eqp++;
    if (kept) mybits |= (1u << j);
  }
  atomicOr(&wbuf[tid >> 2], mybits << ((tid & 3) * 8));
  if (mybits) atomicMin(&sMin, base + __ffs(mybits) - 1);
  __syncthreads();
  if (tid < 64) keepw[(size_t)bh * 64 + tid] = wbuf[tid];
  if (tid == 0) jminb[bh] = sMin;
}

// ---------------- flash attention, flash-decoding style key-split ----------------
// Work item = one wave = (bh, 16-row tile, key-part). Tiles 64..127 and tile 0 are
// "big": split into 2 key-halves producing partial (m,l,O) merged by combine_kernel.
// Tiles 1..63 are "small": single wave, writes attn_out directly.
//
// Per-chunk schedule (vmcnt-in-order aware): issue V(cur) first, then prefetch
// K/pb/kw(next) into the other ping-pong buffer, then QK MFMAs (their K was
// drained by last chunk's V wait -> no wait), scores (pb wait leaves V+next
// outstanding), skip-rescale softmax, PV (V wait leaves next-K/pb outstanding).
#define KLOAD(SUF, T)                                                          \
  do {                                                                         \
    int kb0_ = (T) * 32;                                                       \
    const short* kp_ = kb_bh + (size_t)(kb0_ + lq) * DD + lg * 8;              \
    a0##SUF = *(const bf16x8*)kp_;                                             \
    a1##SUF = *(const bf16x8*)(kp_ + 32);                                      \
    a2##SUF = *(const bf16x8*)(kp_ + 16 * DD);                                 \
    a3##SUF = *(const bf16x8*)(kp_ + 16 * DD + 32);                            \
  } while (0)

#define PBLOAD(SUF, T)                                                         \
  do {                                                                         \
    int kb0_ = (T) * 32;                                                       \
    pb0##SUF = *(const float4_t*)(pbrow + kb0_ + lg * 4);                      \
    pb1##SUF = *(const float4_t*)(pbrow + kb0_ + 16 + lg * 4);                 \
    kw##SUF = kwp[T];                                                          \
  } while (0)

#define CHUNKF(SUF, OSUF, T)                                                   \
  do {                                                                         \
    int kb0c = (T) * 32;                                                       \
    /* V JIT issue: consumed last, latency hides under softmax */              \
    const short* vp_ = vT_bh + kb0c + lg * 8;                                  \
    bf16x8 v0 = *(const bf16x8*)(vp_);                                         \
    bf16x8 v1 = *(const bf16x8*)(vp_ + 16 * NSEQ);                             \
    bf16x8 v2 = *(const bf16x8*)(vp_ + 32 * NSEQ);                             \
    bf16x8 v3 = *(const bf16x8*)(vp_ + 48 * NSEQ);                             \
    /* prefetch next chunk into the other buffer */                            \
    if ((T) + 1 < t1) {                                                        \
      KLOAD(OSUF, (T) + 1);                                                    \
      PBLOAD(OSUF, (T) + 1);                                                   \
    }                                                                          \
    f32x4 s0 = (f32x4){0.f, 0.f, 0.f, 0.f};                                    \
    s0 = mfma16(a0##SUF, qf0, s0);                                             \
    s0 = mfma16(a1##SUF, qf1, s0);                                             \
    f32x4 s1 = (f32x4){0.f, 0.f, 0.f, 0.f};                                    \
    s1 = mfma16(a2##SUF, qf0, s1);                                             \
    s1 = mfma16(a3##SUF, qf1, s1);                                             \
    float cm = -FLT_MAX;                                                       \
    float sv[8];                                                               \
    unsigned vb = 0;                                                           \
    _Pragma("unroll") for (int r = 0; r < 4; ++r) {                            \
      int j0_ = kb0c + lg * 4 + r;                                             \
      unsigned keep0 = (kw##SUF >> (lg * 4 + r)) & 1u;                         \
      float x0 = (keep0 && j0_ <= qglob) ? fmaf(s0[r], 0.125f, pb0##SUF[r])    \
                                         : -FLT_MAX;                           \
      vb |= keep0 << r;                                                        \
      sv[r] = x0;                                                              \
      cm = fmaxf(cm, x0);                                                      \
      unsigned keep1 = (kw##SUF >> (16 + lg * 4 + r)) & 1u;                    \
      float x1 = (keep1 && j0_ + 16 <= qglob)                                  \
                     ? fmaf(s1[r], 0.125f, pb1##SUF[r])                        \
                     : -FLT_MAX;                                               \
      vb |= keep1 << (4 + r);                                                  \
      sv[4 + r] = x1;                                                          \
      cm = fmaxf(cm, x1);                                                      \
    }                                                                          \
    /* skip-rescale: mrun invariant = row max (same in all 4 lane groups). */  \
    /* Rare path only when a new max appears anywhere in the wave. */          \
    if (__any(cm > mrun)) {                                                    \
      float rm = fmaxf(cm, __shfl_xor(cm, 16));                                \
      rm = fmaxf(rm, __shfl_xor(rm, 32));                                      \
      float mnew = fmaxf(mrun, rm);                                            \
      float fsc = __expf(mrun - mnew);                                         \
      mrun = mnew;                                                             \
      lsum *= fsc;                                                             \
      float f0 = __shfl(fsc, lg * 4 + 0);                                      \
      float f1 = __shfl(fsc, lg * 4 + 1);                                      \
      float f2 = __shfl(fsc, lg * 4 + 2);                                      \
      float f3 = __shfl(fsc, lg * 4 + 3);                                      \
      o0[0] *= f0; o0[1] *= f1; o0[2] *= f2; o0[3] *= f3;                      \
      o1[0] *= f0; o1[1] *= f1; o1[2] *= f2; o1[3] *= f3;                      \
      o2[0] *= f0; o2[1] *= f1; o2[2] *= f2; o2[3] *= f3;                      \
      o3[0] *= f0; o3[1] *= f1; o3[2] *= f2; o3[3] *= f3;                      \
    }                                                                          \
    float psum = 0.f;                                                          \
    short4_t pw0, pw1;                                                         \
    _Pragma("unroll") for (int j2 = 0; j2 < 4; ++j2) {                         \
      float pv = ((vb >> j2) & 1u) ? __expf(sv[j2] - mrun) : 0.f;              \
      psum += pv;                                                              \
      pw0[j2] = f2bf(pv);                                                      \
    }                                                                          \
    _Pragma("unroll") for (int j2 = 0; j2 < 4; ++j2) {                         \
      float pv = ((vb >> (4 + j2)) & 1u) ? __expf(sv[4 + j2] - mrun) : 0.f;    \
      psum += pv;                                                              \
      pw1[j2] = f2bf(pv);                                                      \
    }                                                                          \
    lsum += psum;                                                              \
    *(short4_t*)(myp + lq * 72 + lg * 8) = pw0;                                \
    *(short4_t*)(myp + lq * 72 + 32 + lg * 8) = pw1;                           \
    bf16x8 pa = *(const bf16x8*)(myp + lq * 72 + lg * 16);                     \
    o0 = mfma16(pa, v0, o0);                                                   \
    o1 = mfma16(pa, v1, o1);                                                   \
    o2 = mfma16(pa, v2, o2);                                                   \
    o3 = mfma16(pa, v3, o3);                                                   \
  } while (0)

__global__ __launch_bounds__(128, 4) void attn_split_kernel(
    const short* __restrict__ qb, const short* __restrict__ kb,
    const short* __restrict__ vT, const unsigned* __restrict__ keepw,
    const int* __restrict__ jminb, const float* __restrict__ pos_bias,
    short* __restrict__ Opart, float* __restrict__ mlb,
    short* __restrict__ attn_out) {
  __shared__ short pls[2][16][36];   // per-wave P bounce, rows padded to 72B
  int w = threadIdx.x >> 6, lane = threadIdx.x & 63;
  int lq = lane & 15, lg = lane >> 4;
  int gid = blockIdx.x * 2 + w;      // 0..6175

  int bh, tile, part;
  if (gid < 4160) {                  // big halves, heavy-first
    bh = gid & 31;
    int rem = gid >> 5;              // 0..129
    int trank = rem >> 1;            // 0..64
    tile = (trank < 64) ? (127 - trank) : 0;
    part = rem & 1;
  } else {                           // small tiles, descending
    int g2 = gid - 4160;
    bh = g2 & 31;
    tile = 63 - (g2 >> 5);           // 63..1
    part = 0;
  }
  int b = bh >> 4, h = bh & 15;
  int q0 = tile << 4;
  int qglob = q0 + lq;

  int jmin = jminb[bh];
  int bound = (q0 < jmin) ? NSEQ : (q0 + 16);
  int nkb = (bound + 31) >> 5;
  int t0 = 0, t1 = nkb;
  bool big = (tile >= 64) || (tile == 0);
  if (big) {
    int half = nkb >> 1;
    if (part) t0 = half; else t1 = half;
  }

  const short* qp = qb + ((size_t)bh * NSEQ + qglob) * DD;
  bf16x8 qf0 = *(const bf16x8*)(qp + lg * 8);
  bf16x8 qf1 = *(const bf16x8*)(qp + 32 + lg * 8);

  const short* kb_bh = kb + (size_t)bh * NSEQ * DD;
  const short* vT_bh = vT + ((size_t)bh * DD + lq) * NSEQ;
  const float* pbrow = pos_bias + ((size_t)h * NSEQ + qglob) * NSEQ;
  const unsigned* kwp = keepw + (size_t)bh * 64;
  char* myp = (char*)&pls[w][0][0];

  float mrun = -FLT_MAX, lsum = 0.f;
  f32x4 o0 = (f32x4){0.f, 0.f, 0.f, 0.f}, o1 = o0, o2 = o0, o3 = o0;

  bf16x8 a0A, a1A, a2A, a3A, a0B, a1B, a2B, a3B;
  float4_t pb0A, pb1A, pb0B, pb1B;
  unsigned kwA, kwB;

  if (t0 < t1) {
    KLOAD(A, t0);
    PBLOAD(A, t0);
    int t = t0;
    for (;;) {
      CHUNKF(A, B, t);
      if (++t >= t1) break;
      CHUNKF(B, A, t);
      if (++t >= t1) break;
    }
  }

  if (big) {
    // lsum is per-lane (each lane covers 8 of the 32 chunk keys): reduce the
    // 4 lane-groups to the full row sum BEFORE writing the partial.
    float lrow = lsum;
    lrow += __shfl_xor(lrow, 16);
    lrow += __shfl_xor(lrow, 32);
    int t65 = (tile >= 64) ? (tile - 64) : 64;
    int pidx = ((bh * 65 + t65) << 1) + part;
    if (lg == 0) {
      mlb[pidx * 32 + lq] = mrun;
      mlb[pidx * 32 + 16 + lq] = lrow;
    }
    short* op = Opart + (size_t)pidx * 1024;
#pragma unroll
    for (int r = 0; r < 4; ++r) {
      int row = lg * 4 + r;
      op[row * 64 + lq]      = f2bf(o0[r]);
      op[row * 64 + lq + 16] = f2bf(o1[r]);
      op[row * 64 + lq + 32] = f2bf(o2[r]);
      op[row * 64 + lq + 48] = f2bf(o3[r]);
    }
  } else {
    float ltot = lsum;
    ltot += __shfl_xor(ltot, 16);
    ltot += __shfl_xor(ltot, 32);
    float inv = 1.f / ltot;
    float i0 = __shfl(inv, lg * 4 + 0);
    float i1 = __shfl(inv, lg * 4 + 1);
    float i2 = __shfl(inv, lg * 4 + 2);
    float i3 = __shfl(inv, lg * 4 + 3);
    short* ob = attn_out + ((size_t)b * NSEQ + q0 + lg * 4) * CDIM + h * DD + lq;
#pragma unroll
    for (int r = 0; r < 4; ++r) {
      float ir = (r == 0) ? i0 : (r == 1) ? i1 : (r == 2) ? i2 : i3;
      short* orow = ob + (size_t)r * CDIM;
      orow[0]  = f2bf(o0[r] * ir);
      orow[16] = f2bf(o1[r] * ir);
      orow[32] = f2bf(o2[r] * ir);
      orow[48] = f2bf(o3[r] * ir);
    }
  }
}

// ---------------- combine partials for big tiles ----------------
__global__ __launch_bounds__(64) void combine_kernel(
    const float* __restrict__ mlb, const short* __restrict__ Opart,
    short* __restrict__ attn_out) {
  int blk = blockIdx.x;              // 0..2079
  int bh = blk & 31, t65 = blk >> 5; // t65 0..64
  int tile = (t65 < 64) ? (64 + t65) : 0;
  int b = bh >> 4, h = bh & 15;
  int lane = threadIdx.x;
  int row = lane >> 2, c0 = (lane & 3) * 16;
  int p0 = (bh * 65 + t65) << 1, p1 = p0 + 1;
  float m0 = mlb[p0 * 32 + row], l0 = mlb[p0 * 32 + 16 + row];
  float m1 = mlb[p1 * 32 + row], l1 = mlb[p1 * 32 + 16 + row];
  float M = fmaxf(m0, m1);
  float f0 = __expf(m0 - M), f1 = __expf(m1 - M);
  float L = l0 * f0 + l1 * f1;
  float inv = 1.f / L;
  const short* q0p = Opart + (size_t)p0 * 1024 + row * 64 + c0;
  const short* q1p = Opart + (size_t)p1 * 1024 + row * 64 + c0;
  short8_t x0a = *(const short8_t*)q0p;
  short8_t x0b = *(const short8_t*)(q0p + 8);
  short8_t x1a = *(const short8_t*)q1p;
  short8_t x1b = *(const short8_t*)(q1p + 8);
  short* orow = attn_out + ((size_t)b * NSEQ + tile * 16 + row) * CDIM + h * DD + c0;
  short8_t oa, ob;
#pragma unroll
  for (int j = 0; j < 8; ++j) {
    float a = bf2f(x0a[j]) * f0 + bf2f(x1a[j]) * f1;
    oa[j] = f2bf(a * inv);
  }
#pragma unroll
  for (int j = 0; j < 8; ++j) {
    float a = bf2f(x0b[j]) * f0 + bf2f(x1b[j]) * f1;
    ob[j] = f2bf(a * inv);
  }
  *(short8_t*)orow = oa;
  *(short8_t*)(orow + 8) = ob;
}

// ---------------- launch ----------------
extern "C" void kernel_launch(void* const* d_in, const int* in_sizes, int n_in,
                              void* d_out, int out_size, void* d_ws, size_t ws_size,
                              hipStream_t stream) {
  const float* x        = (const float*)d_in[0];
  const float* Wqkv     = (const float*)d_in[1];
  const float* Wout     = (const float*)d_in[2];
  const float* pos_bias = (const float*)d_in[3];
  const int*   seq_mask = (const int*)d_in[4];
  float* out = (float*)d_out;

  char* ws = (char*)d_ws;
  short* xb    = (short*)(ws);                          // 8 MB  x bf16 (dead after GEMM0)
  short* wqkvb = (short*)(ws + ((size_t)8  << 20));     // 6 MB  W_qkv bf16 (dead after GEMM0)
  short* woutb = (short*)(ws + ((size_t)14 << 20));     // 2 MB  W_out bf16
  short* qb    = (short*)(ws + ((size_t)16 << 20));     // 8 MB  q bf16 [B,H,N,D]
  short* kbuf  = (short*)(ws + ((size_t)24 << 20));     // 8 MB  k bf16 [B,H,N,D]
  short* vTb   = (short*)(ws + ((size_t)32 << 20));     // 8 MB  vT bf16 [B,H,D,N]
  unsigned* keepw = (unsigned*)(ws + ((size_t)40 << 20)); // 8 KB keep bitmap [BH,64]
  int* jminb   = (int*)(ws + ((size_t)40 << 20) + 65536); // 128 B jmin [BH]
  short* aob   = (short*)(ws + ((size_t)41 << 20));     // 8 MB  attn_out bf16
  // partials overlay xb/wqkvb (temporally disjoint: written by attn, after GEMM0)
  short* Opart = (short*)(ws);                          // 4160 * 1024 shorts = 8.125 MB
  float* mlb   = (float*)(ws + ((size_t)17 << 19));     // at 8.5 MB, 4160*128B

  cast_f32_bf16_kernel<<<4096, 256, 0, stream>>>(x, xb, (BB * NSEQ * CDIM) / 4);
  cast_wqkv_kernel<<<3072, 256, 0, stream>>>(Wqkv, wqkvb);
  cast_f32_bf16_kernel<<<1024, 256, 0, stream>>>(Wout, woutb, (CDIM * HH * DD) / 4);

  gemm_bt_kernel<0><<<dim3(24, 32), 256, 0, stream>>>(xb, wqkvb, CDIM, 3 * HH * DD,
                                                      nullptr, qb, kbuf, vTb);

  topk_kernel<<<BB * HH, 256, 0, stream>>>(seq_mask, keepw, jminb);

  attn_split_kernel<<<3088, 128, 0, stream>>>(qb, kbuf, vTb, keepw, jminb,
                                              pos_bias, Opart, mlb, aob);

  combine_kernel<<<2080, 64, 0, stream>>>(mlb, Opart, aob);

  gemm_bt_kernel<1><<<dim3(8, 32), 256, 0, stream>>>(aob, woutb, HH * DD, CDIM,
                                                     out, nullptr, nullptr, nullptr);
}

// Round 8
// 257.872 us; speedup vs baseline: 1.2981x; 1.2981x over previous
//
#include <hip/hip_runtime.h>
#include <hip/hip_bf16.h>
#include <float.h>

// Problem constants
#define BB    2
#define NSEQ  2048
#define CDIM  1024
#define HH    16
#define DD    64
#define KKEEP 1228

typedef __attribute__((ext_vector_type(8))) short short8_t;
typedef __attribute__((ext_vector_type(4))) short short4_t;
typedef __attribute__((ext_vector_type(4))) float f32x4;
typedef __attribute__((ext_vector_type(4))) float float4_t;
typedef __bf16 bf16x8 __attribute__((ext_vector_type(8)));

static __device__ __forceinline__ short f2bf(float x) {
  __hip_bfloat16 h = __float2bfloat16(x);
  short s;
  __builtin_memcpy(&s, &h, 2);
  return s;
}

static __device__ __forceinline__ float bf2f(short s) {
  unsigned u = ((unsigned)(unsigned short)s) << 16;
  float f;
  __builtin_memcpy(&f, &u, 4);
  return f;
}

static __device__ __forceinline__ f32x4 mfma16(bf16x8 a, bf16x8 b, f32x4 c) {
  return __builtin_amdgcn_mfma_f32_16x16x32_bf16(a, b, c, 0, 0, 0);
}

// ---------------- cast kernels ----------------
__global__ __launch_bounds__(256) void cast_f32_bf16_kernel(
    const float* __restrict__ src, short* __restrict__ dst, int n4) {
  int i = blockIdx.x * 256 + threadIdx.x;
  if (i >= n4) return;
  float4_t v = ((const float4_t*)src)[i];
  short4_t o;
  o[0] = f2bf(v[0]); o[1] = f2bf(v[1]); o[2] = f2bf(v[2]); o[3] = f2bf(v[3]);
  ((short4_t*)dst)[i] = o;
}

// Permute W_qkv rows: dst row rr = c*1024 + h*64 + d  <-  src row h*192 + d*3 + c
__global__ __launch_bounds__(256) void cast_wqkv_kernel(
    const float* __restrict__ w, short* __restrict__ dst) {
  int rr = blockIdx.x;              // 0..3071
  int c = rr >> 10, hd = rr & 1023;
  int h = hd >> 6, d = hd & 63;
  int srow = h * 192 + d * 3 + c;
  int col = threadIdx.x * 4;
  float4_t v = *(const float4_t*)(w + (size_t)srow * CDIM + col);
  short4_t o;
  o[0] = f2bf(v[0]); o[1] = f2bf(v[1]); o[2] = f2bf(v[2]); o[3] = f2bf(v[3]);
  *(short4_t*)(dst + (size_t)rr * CDIM + col) = o;
}

// ---------------- GEMM: C[M,N] = A[M,K] * B[N,K]^T (both bf16, fp32 acc) ----------------
template <int EPI>
__global__ __launch_bounds__(256) void gemm_bt_kernel(
    const short* __restrict__ A, const short* __restrict__ B, int K, int N,
    float* __restrict__ outF, short* __restrict__ outQ,
    short* __restrict__ outK, short* __restrict__ outV) {
  __shared__ short lA[128 * 32];
  __shared__ short lB[128 * 32];
  int m0 = blockIdx.y * 128, n0 = blockIdx.x * 128;
  int tid = threadIdx.x, lane = tid & 63;
  int w = tid >> 6;
  int lq = lane & 15, lg = lane >> 4;
  int wm = w >> 1, wn = w & 1;

  f32x4 acc[4][4];
#pragma unroll
  for (int m = 0; m < 4; ++m)
#pragma unroll
    for (int n = 0; n < 4; ++n) acc[m][n] = (f32x4){0.f, 0.f, 0.f, 0.f};

  const int c0 = tid, c1 = tid + 256;
  for (int k0 = 0; k0 < K; k0 += 32) {
    short8_t a0 = *(const short8_t*)(A + (size_t)(m0 + (c0 >> 2)) * K + k0 + (c0 & 3) * 8);
    short8_t a1 = *(const short8_t*)(A + (size_t)(m0 + (c1 >> 2)) * K + k0 + (c1 & 3) * 8);
    short8_t b0 = *(const short8_t*)(B + (size_t)(n0 + (c0 >> 2)) * K + k0 + (c0 & 3) * 8);
    short8_t b1 = *(const short8_t*)(B + (size_t)(n0 + (c1 >> 2)) * K + k0 + (c1 & 3) * 8);
    *(short8_t*)(lA + c0 * 8) = a0;
    *(short8_t*)(lA + c1 * 8) = a1;
    *(short8_t*)(lB + c0 * 8) = b0;
    *(short8_t*)(lB + c1 * 8) = b1;
    __syncthreads();
    bf16x8 af[4], bf[4];
#pragma unroll
    for (int m = 0; m < 4; ++m)
      af[m] = *(const bf16x8*)(lA + (wm * 64 + m * 16 + lq) * 32 + lg * 8);
#pragma unroll
    for (int n = 0; n < 4; ++n)
      bf[n] = *(const bf16x8*)(lB + (wn * 64 + n * 16 + lq) * 32 + lg * 8);
#pragma unroll
    for (int m = 0; m < 4; ++m)
#pragma unroll
      for (int n = 0; n < 4; ++n) acc[m][n] = mfma16(af[m], bf[n], acc[m][n]);
    __syncthreads();
  }

#pragma unroll
  for (int m = 0; m < 4; ++m)
#pragma unroll
    for (int n = 0; n < 4; ++n) {
      int row_b = m0 + wm * 64 + m * 16 + lg * 4;
      int col = n0 + wn * 64 + n * 16 + lq;
#pragma unroll
      for (int r = 0; r < 4; ++r) {
        float v = acc[m][n][r];
        int row = row_b + r;
        if constexpr (EPI == 1) {
          outF[(size_t)row * N + col] = v;
        } else {
          int c = col >> 10, cc = col & 1023;
          int bb2 = row >> 11, nn = row & 2047;
          int hh2 = cc >> 6, dd2 = cc & 63;
          short val = f2bf(v);
          if (c == 0)
            outQ[((size_t)(bb2 * HH + hh2) * NSEQ + nn) * DD + dd2] = val;
          else if (c == 1)
            outK[((size_t)(bb2 * HH + hh2) * NSEQ + nn) * DD + dd2] = val;
          else
            outV[((size_t)(bb2 * HH + hh2) * DD + dd2) * NSEQ + nn] = val;
        }
      }
    }
}

// ---------------- top-k selection -> keep bitmap + jmin (stable: value desc, index asc) ----
__global__ __launch_bounds__(256) void topk_kernel(const int* __restrict__ seq_mask,
                                                   unsigned* __restrict__ keepw,
                                                   int* __restrict__ jminb) {
  __shared__ int hist[10];
  __shared__ int vals[NSEQ];
  __shared__ int seqc[256];
  __shared__ unsigned wbuf[64];
  __shared__ int sT, sNeed, sMin;
  int bh = blockIdx.x, tid = threadIdx.x;
  if (tid < 10) hist[tid] = 0;
  if (tid < 64) wbuf[tid] = 0;
  if (tid == 0) sMin = NSEQ;
  __syncthreads();
  const int* sm = seq_mask + (size_t)bh * NSEQ;
  for (int i = tid; i < NSEQ; i += 256) {
    int v = sm[i];
    vals[i] = v;
    atomicAdd(&hist[v], 1);
  }
  __syncthreads();
  if (tid == 0) {
    int cum = 0, t = 0;
    for (int v = 9; v >= 0; --v) {
      int hv = hist[v];
      if (cum + hv >= KKEEP) { t = v; break; }
      cum += hv;
    }
    sT = t;
    sNeed = KKEEP - cum;   // ties (value==t) kept, lowest indices first
  }
  __syncthreads();
  int t = sT, need = sNeed;
  int base = tid * 8, leq = 0;
  int lv[8];
#pragma unroll
  for (int j = 0; j < 8; ++j) {
    lv[j] = vals[base + j];
    leq += (lv[j] == t);
  }
  seqc[tid] = leq;
  __syncthreads();
  for (int off = 1; off < 256; off <<= 1) {
    int a = 0;
    if (tid >= off) a = seqc[tid - off];
    __syncthreads();
    seqc[tid] += a;
    __syncthreads();
  }
  int eqp = seqc[tid] - leq;  // exclusive prefix of (v==t)
  unsigned mybits = 0;
#pragma unroll
  for (int j = 0; j < 8; ++j) {
    int v = lv[j];
    bool kept = (v > t) || (v == t && eqp < need);
    if (v == t) eqp++;
    if (kept) mybits |= (1u << j);
  }
  atomicOr(&wbuf[tid >> 2], mybits << ((tid & 3) * 8));
  if (mybits) atomicMin(&sMin, base + __ffs(mybits) - 1);
  __syncthreads();
  if (tid < 64) keepw[(size_t)bh * 64 + tid] = wbuf[tid];
  if (tid == 0) jminb[bh] = sMin;
}

// ---------------- flash attention, flash-decoding style key-split ----------------
// Work item = one wave = (bh, 16-row tile, key-part). Tiles 64..127 and tile 0 are
// "big": split into 2 key-halves producing partial (m,l,O) merged by combine_kernel.
// Tiles 1..63 are "small": single wave, writes attn_out directly.
//
// vmcnt-in-order-aware per-chunk schedule: issue K(cur), V(cur), THEN pb(next).
// QK's K-wait drains only K (pb(next) issued after); PV's V-wait leaves pb(next)
// in flight. (Round-6 bug: pb(next) issued BEFORE K(cur) -> the K-wait drained
// pb's ~900cy HBM latency synchronously every chunk.)
#define PBLOAD(SUF, T)                                                         \
  do {                                                                         \
    int kb0_ = (T) * 32;                                                       \
    pb0##SUF = *(const float4_t*)(pbrow + kb0_ + lg * 4);                      \
    pb1##SUF = *(const float4_t*)(pbrow + kb0_ + 16 + lg * 4);                 \
    kw##SUF = kwp[T];                                                          \
  } while (0)

#define CHUNKS(SUF, OSUF, T)                                                   \
  do {                                                                         \
    int kb0c = (T) * 32;                                                       \
    const short* kp_ = kb_bh + (size_t)(kb0c + lq) * DD + lg * 8;              \
    bf16x8 a0 = *(const bf16x8*)kp_;                                           \
    bf16x8 a1 = *(const bf16x8*)(kp_ + 32);                                    \
    bf16x8 a2 = *(const bf16x8*)(kp_ + 16 * DD);                               \
    bf16x8 a3 = *(const bf16x8*)(kp_ + 16 * DD + 32);                          \
    const short* vp_ = vT_bh + kb0c + lg * 8;                                  \
    bf16x8 v0 = *(const bf16x8*)(vp_);                                         \
    bf16x8 v1 = *(const bf16x8*)(vp_ + 16 * NSEQ);                             \
    bf16x8 v2 = *(const bf16x8*)(vp_ + 32 * NSEQ);                             \
    bf16x8 v3 = *(const bf16x8*)(vp_ + 48 * NSEQ);                             \
    if ((T) + 1 < t1) PBLOAD(OSUF, (T) + 1);                                   \
    f32x4 s0 = (f32x4){0.f, 0.f, 0.f, 0.f};                                    \
    s0 = mfma16(a0, qf0, s0);                                                  \
    s0 = mfma16(a1, qf1, s0);                                                  \
    f32x4 s1 = (f32x4){0.f, 0.f, 0.f, 0.f};                                    \
    s1 = mfma16(a2, qf0, s1);                                                  \
    s1 = mfma16(a3, qf1, s1);                                                  \
    float cm = -FLT_MAX;                                                       \
    float sv[8];                                                               \
    unsigned vb = 0;                                                           \
    _Pragma("unroll") for (int r = 0; r < 4; ++r) {                            \
      int j0_ = kb0c + lg * 4 + r;                                             \
      unsigned keep0 = (kw##SUF >> (lg * 4 + r)) & 1u;                         \
      float x0 = (keep0 && j0_ <= qglob) ? fmaf(s0[r], 0.125f, pb0##SUF[r])    \
                                         : -FLT_MAX;                           \
      vb |= keep0 << r;                                                        \
      sv[r] = x0;                                                              \
      cm = fmaxf(cm, x0);                                                      \
      unsigned keep1 = (kw##SUF >> (16 + lg * 4 + r)) & 1u;                    \
      float x1 = (keep1 && j0_ + 16 <= qglob)                                  \
                     ? fmaf(s1[r], 0.125f, pb1##SUF[r])                        \
                     : -FLT_MAX;                                               \
      vb |= keep1 << (4 + r);                                                  \
      sv[4 + r] = x1;                                                          \
      cm = fmaxf(cm, x1);                                                      \
    }                                                                          \
    /* skip-rescale: mrun invariant = running row max (uniform across wave) */ \
    if (__any(cm > mrun)) {                                                    \
      float rm = fmaxf(cm, __shfl_xor(cm, 16));                                \
      rm = fmaxf(rm, __shfl_xor(rm, 32));                                      \
      float mnew = fmaxf(mrun, rm);                                            \
      float fsc = __expf(mrun - mnew);                                         \
      mrun = mnew;                                                             \
      lsum *= fsc;                                                             \
      float f0 = __shfl(fsc, lg * 4 + 0);                                      \
      float f1 = __shfl(fsc, lg * 4 + 1);                                      \
      float f2 = __shfl(fsc, lg * 4 + 2);                                      \
      float f3 = __shfl(fsc, lg * 4 + 3);                                      \
      o0[0] *= f0; o0[1] *= f1; o0[2] *= f2; o0[3] *= f3;                      \
      o1[0] *= f0; o1[1] *= f1; o1[2] *= f2; o1[3] *= f3;                      \
      o2[0] *= f0; o2[1] *= f1; o2[2] *= f2; o2[3] *= f3;                      \
      o3[0] *= f0; o3[1] *= f1; o3[2] *= f2; o3[3] *= f3;                      \
    }                                                                          \
    float psum = 0.f;                                                          \
    short4_t pw0, pw1;                                                         \
    _Pragma("unroll") for (int j2 = 0; j2 < 4; ++j2) {                         \
      float pv = ((vb >> j2) & 1u) ? __expf(sv[j2] - mrun) : 0.f;              \
      psum += pv;                                                              \
      pw0[j2] = f2bf(pv);                                                      \
    }                                                                          \
    _Pragma("unroll") for (int j2 = 0; j2 < 4; ++j2) {                         \
      float pv = ((vb >> (4 + j2)) & 1u) ? __expf(sv[4 + j2] - mrun) : 0.f;    \
      psum += pv;                                                              \
      pw1[j2] = f2bf(pv);                                                      \
    }                                                                          \
    lsum += psum;                                                              \
    *(short4_t*)(myp + lq * 72 + lg * 8) = pw0;                                \
    *(short4_t*)(myp + lq * 72 + 32 + lg * 8) = pw1;                           \
    bf16x8 pa = *(const bf16x8*)(myp + lq * 72 + lg * 16);                     \
    o0 = mfma16(pa, v0, o0);                                                   \
    o1 = mfma16(pa, v1, o1);                                                   \
    o2 = mfma16(pa, v2, o2);                                                   \
    o3 = mfma16(pa, v3, o3);                                                   \
  } while (0)

__global__ __launch_bounds__(128) void attn_split_kernel(
    const short* __restrict__ qb, const short* __restrict__ kb,
    const short* __restrict__ vT, const unsigned* __restrict__ keepw,
    const int* __restrict__ jminb, const float* __restrict__ pos_bias,
    short* __restrict__ Opart, float* __restrict__ mlb,
    short* __restrict__ attn_out) {
  __shared__ short pls[2][16][36];   // per-wave P bounce, rows padded to 72B
  int w = threadIdx.x >> 6, lane = threadIdx.x & 63;
  int lq = lane & 15, lg = lane >> 4;

  // bh-locality XCD mapping: dispatch round-robins XCDs (xcd = blockIdx % 8);
  // each XCD owns 4 bh (K/V working set 2 MB -> L2-resident), cycling them
  // heavy-first. Perf heuristic only; correctness placement-independent.
  int xcd = blockIdx.x & 7;
  int j = (blockIdx.x >> 3) * 2 + w;   // 0..771 within this XCD
  int bh = xcd * 4 + (j & 3);
  int r = j >> 2;                      // 0..192 heavy-first rank within bh
  int tile, part;
  if (r < 130) {                       // big halves
    int trank = r >> 1;                // 0..64
    tile = (trank < 64) ? (127 - trank) : 0;
    part = r & 1;
  } else {                             // small tiles, descending 63..1
    tile = 63 - (r - 130);
    part = 0;
  }
  int b = bh >> 4, h = bh & 15;
  int q0 = tile << 4;
  int qglob = q0 + lq;

  int jmin = jminb[bh];
  int bound = (q0 < jmin) ? NSEQ : (q0 + 16);
  int nkb = (bound + 31) >> 5;
  int t0 = 0, t1 = nkb;
  bool big = (tile >= 64) || (tile == 0);
  if (big) {
    int half = nkb >> 1;
    if (part) t0 = half; else t1 = half;
  }

  const short* qp = qb + ((size_t)bh * NSEQ + qglob) * DD;
  bf16x8 qf0 = *(const bf16x8*)(qp + lg * 8);
  bf16x8 qf1 = *(const bf16x8*)(qp + 32 + lg * 8);

  const short* kb_bh = kb + (size_t)bh * NSEQ * DD;
  const short* vT_bh = vT + ((size_t)bh * DD + lq) * NSEQ;
  const float* pbrow = pos_bias + ((size_t)h * NSEQ + qglob) * NSEQ;
  const unsigned* kwp = keepw + (size_t)bh * 64;
  char* myp = (char*)&pls[w][0][0];

  float mrun = -FLT_MAX, lsum = 0.f;
  f32x4 o0 = (f32x4){0.f, 0.f, 0.f, 0.f}, o1 = o0, o2 = o0, o3 = o0;

  float4_t pb0A, pb1A, pb0B, pb1B;
  unsigned kwA, kwB;

  if (t0 < t1) {
    PBLOAD(A, t0);
    int t = t0;
    for (;;) {
      CHUNKS(A, B, t);
      if (++t >= t1) break;
      CHUNKS(B, A, t);
      if (++t >= t1) break;
    }
  }

  if (big) {
    // lsum is per-lane (each lane covers 8 of the 32 chunk keys): reduce the
    // 4 lane-groups to the full row sum BEFORE writing the partial.
    float lrow = lsum;
    lrow += __shfl_xor(lrow, 16);
    lrow += __shfl_xor(lrow, 32);
    int t65 = (tile >= 64) ? (tile - 64) : 64;
    int pidx = ((bh * 65 + t65) << 1) + part;
    if (lg == 0) {
      mlb[pidx * 32 + lq] = mrun;
      mlb[pidx * 32 + 16 + lq] = lrow;
    }
    short* op = Opart + (size_t)pidx * 1024;
#pragma unroll
    for (int rr = 0; rr < 4; ++rr) {
      int row = lg * 4 + rr;
      op[row * 64 + lq]      = f2bf(o0[rr]);
      op[row * 64 + lq + 16] = f2bf(o1[rr]);
      op[row * 64 + lq + 32] = f2bf(o2[rr]);
      op[row * 64 + lq + 48] = f2bf(o3[rr]);
    }
  } else {
    float ltot = lsum;
    ltot += __shfl_xor(ltot, 16);
    ltot += __shfl_xor(ltot, 32);
    float inv = 1.f / ltot;
    float i0 = __shfl(inv, lg * 4 + 0);
    float i1 = __shfl(inv, lg * 4 + 1);
    float i2 = __shfl(inv, lg * 4 + 2);
    float i3 = __shfl(inv, lg * 4 + 3);
    short* ob = attn_out + ((size_t)b * NSEQ + q0 + lg * 4) * CDIM + h * DD + lq;
#pragma unroll
    for (int rr = 0; rr < 4; ++rr) {
      float ir = (rr == 0) ? i0 : (rr == 1) ? i1 : (rr == 2) ? i2 : i3;
      short* orow = ob + (size_t)rr * CDIM;
      orow[0]  = f2bf(o0[rr] * ir);
      orow[16] = f2bf(o1[rr] * ir);
      orow[32] = f2bf(o2[rr] * ir);
      orow[48] = f2bf(o3[rr] * ir);
    }
  }
}

// ---------------- combine partials for big tiles ----------------
__global__ __launch_bounds__(64) void combine_kernel(
    const float* __restrict__ mlb, const short* __restrict__ Opart,
    short* __restrict__ attn_out) {
  int blk = blockIdx.x;              // 0..2079
  int bh = blk & 31, t65 = blk >> 5; // t65 0..64
  int tile = (t65 < 64) ? (64 + t65) : 0;
  int b = bh >> 4, h = bh & 15;
  int lane = threadIdx.x;
  int row = lane >> 2, c0 = (lane & 3) * 16;
  int p0 = (bh * 65 + t65) << 1, p1 = p0 + 1;
  float m0 = mlb[p0 * 32 + row], l0 = mlb[p0 * 32 + 16 + row];
  float m1 = mlb[p1 * 32 + row], l1 = mlb[p1 * 32 + 16 + row];
  float M = fmaxf(m0, m1);
  float f0 = __expf(m0 - M), f1 = __expf(m1 - M);
  float L = l0 * f0 + l1 * f1;
  float inv = 1.f / L;
  const short* q0p = Opart + (size_t)p0 * 1024 + row * 64 + c0;
  const short* q1p = Opart + (size_t)p1 * 1024 + row * 64 + c0;
  short8_t x0a = *(const short8_t*)q0p;
  short8_t x0b = *(const short8_t*)(q0p + 8);
  short8_t x1a = *(const short8_t*)q1p;
  short8_t x1b = *(const short8_t*)(q1p + 8);
  short* orow = attn_out + ((size_t)b * NSEQ + tile * 16 + row) * CDIM + h * DD + c0;
  short8_t oa, ob;
#pragma unroll
  for (int jj = 0; jj < 8; ++jj) {
    float a = bf2f(x0a[jj]) * f0 + bf2f(x1a[jj]) * f1;
    oa[jj] = f2bf(a * inv);
  }
#pragma unroll
  for (int jj = 0; jj < 8; ++jj) {
    float a = bf2f(x0b[jj]) * f0 + bf2f(x1b[jj]) * f1;
    ob[jj] = f2bf(a * inv);
  }
  *(short8_t*)orow = oa;
  *(short8_t*)(orow + 8) = ob;
}

// ---------------- launch ----------------
extern "C" void kernel_launch(void* const* d_in, const int* in_sizes, int n_in,
                              void* d_out, int out_size, void* d_ws, size_t ws_size,
                              hipStream_t stream) {
  const float* x        = (const float*)d_in[0];
  const float* Wqkv     = (const float*)d_in[1];
  const float* Wout     = (const float*)d_in[2];
  const float* pos_bias = (const float*)d_in[3];
  const int*   seq_mask = (const int*)d_in[4];
  float* out = (float*)d_out;

  char* ws = (char*)d_ws;
  short* xb    = (short*)(ws);                          // 8 MB  x bf16 (dead after GEMM0)
  short* wqkvb = (short*)(ws + ((size_t)8  << 20));     // 6 MB  W_qkv bf16 (dead after GEMM0)
  short* woutb = (short*)(ws + ((size_t)14 << 20));     // 2 MB  W_out bf16
  short* qb    = (short*)(ws + ((size_t)16 << 20));     // 8 MB  q bf16 [B,H,N,D]
  short* kbuf  = (short*)(ws + ((size_t)24 << 20));     // 8 MB  k bf16 [B,H,N,D]
  short* vTb   = (short*)(ws + ((size_t)32 << 20));     // 8 MB  vT bf16 [B,H,D,N]
  unsigned* keepw = (unsigned*)(ws + ((size_t)40 << 20)); // 8 KB keep bitmap [BH,64]
  int* jminb   = (int*)(ws + ((size_t)40 << 20) + 65536); // 128 B jmin [BH]
  short* aob   = (short*)(ws + ((size_t)41 << 20));     // 8 MB  attn_out bf16
  // partials overlay xb/wqkvb (temporally disjoint: written by attn, after GEMM0)
  short* Opart = (short*)(ws);                          // 4160 * 1024 shorts = 8.125 MB
  float* mlb   = (float*)(ws + ((size_t)17 << 19));     // at 8.5 MB, 4160*128B

  cast_f32_bf16_kernel<<<4096, 256, 0, stream>>>(x, xb, (BB * NSEQ * CDIM) / 4);
  cast_wqkv_kernel<<<3072, 256, 0, stream>>>(Wqkv, wqkvb);
  cast_f32_bf16_kernel<<<1024, 256, 0, stream>>>(Wout, woutb, (CDIM * HH * DD) / 4);

  gemm_bt_kernel<0><<<dim3(24, 32), 256, 0, stream>>>(xb, wqkvb, CDIM, 3 * HH * DD,
                                                      nullptr, qb, kbuf, vTb);

  topk_kernel<<<BB * HH, 256, 0, stream>>>(seq_mask, keepw, jminb);

  attn_split_kernel<<<3088, 128, 0, stream>>>(qb, kbuf, vTb, keepw, jminb,
                                              pos_bias, Opart, mlb, aob);

  combine_kernel<<<2080, 64, 0, stream>>>(mlb, Opart, aob);

  gemm_bt_kernel<1><<<dim3(8, 32), 256, 0, stream>>>(aob, woutb, HH * DD, CDIM,
                                                     out, nullptr, nullptr, nullptr);
}